// Round 3
// baseline (319.989 us; speedup 1.0000x reference)
//
#include <hip/hip_runtime.h>

// RIIDModelLSTM: 2-layer LSTM (H=6) over T=512, B=8192, fused FC(6->32->1) head.
//
// Mapping (v3 = v2 + regalloc fix): 16 lanes per sequence, 2 waves/SIMD.
//   lane sub = tid&15; half = sub>>3; k = sub&7 (unit; k=6,7 padded, zero wts)
//   half=0 lane computes gates (i,f) of unit k; half=1 computes (g,o).
//   Gates packed as float2 (v_pk_fma_f32). One xor-8 swizzle swaps activations
//   so both halves hold (i,f,g,o) and redundantly compute c,h.
//   sigma/tanh unified: f(x) = 1 - B*rcp(1 + exp2(S*x)), S folded into weights.
//
// v3 key change: amdgpu_waves_per_eu(2,2). Without it the backend targeted
// 8 waves/SIMD (VGPR_Count=56!) and rematerialized the loop-invariant weight
// loads INSIDE the 512-step loop; the grid only provides 2 waves/SIMD, so
// that was pure per-step reload cost. Pinning the range unlocks 256 VGPRs so
// all ~100 weight/state floats stay register-resident across the scan.

typedef float v2f __attribute__((ext_vector_type(2)));

static constexpr float L2E = 1.44269504088896340736f;

template <int IMM>
__device__ __forceinline__ float swzf(float v) {
    return __int_as_float(__builtin_amdgcn_ds_swizzle(__float_as_int(v), IMM));
}

// broadcast lane ((lane&0x10)|J) of the 32-lane group -> unit J of own sequence
template <int J>
__device__ __forceinline__ float bcast16(float v) {
    return swzf<(J << 5) | 0x10>(v);
}

__device__ __forceinline__ float tanh_fast(float x) {
    float e = __builtin_amdgcn_exp2f((2.0f * L2E) * x);
    return 1.0f - 2.0f * __builtin_amdgcn_rcpf(1.0f + e);
}

extern "C" __global__ void __launch_bounds__(256)
__attribute__((amdgpu_waves_per_eu(2, 2)))
lstm_fused16(const float* __restrict__ x,
             const float* __restrict__ wih0, const float* __restrict__ whh0,
             const float* __restrict__ bih0, const float* __restrict__ bhh0,
             const float* __restrict__ wih1, const float* __restrict__ whh1,
             const float* __restrict__ bih1, const float* __restrict__ bhh1,
             const float* __restrict__ fc1w_g, const float* __restrict__ fc1b_g,
             const float* __restrict__ fc2w_g, const float* __restrict__ fc2b_g,
             float* __restrict__ out, int nbatch)
{
    const int tid  = blockIdx.x * blockDim.x + threadIdx.x;
    const int sub  = tid & 15;       // lane within sequence group
    const int seq  = tid >> 4;       // sequence index
    if (seq >= nbatch) return;

    const int   half = sub >> 3;     // 0: gates (i,f); 1: gates (g,o)
    const int   k    = sub & 7;      // hidden unit
    const float km   = (k < 6) ? 1.0f : 0.0f;   // pad lanes 6,7 -> zero weights
    const int   kk   = (k < 6) ? k : 0;

    // activation params: f(x)=1-B*rcp(1+exp2(S*x)); S folded into weights.
    // .x gate: sigmoid (half=0) or tanh (half=1); .y gate: always sigmoid.
    const float Bx  = half ? 2.0f : 1.0f;
    const float sxw = km * (half ? (2.0f * L2E) : L2E);
    const float syw = km * L2E;

    // ---- per-lane weights (gate rows 2*half, 2*half+1 of unit kk), pre-scaled
    const int r0 = (2 * half    ) * 6 + kk;
    const int r1 = (2 * half + 1) * 6 + kk;

    v2f wi0[6], wh0[6], wi1[6], wh1[6];
#pragma unroll
    for (int j = 0; j < 6; ++j) {
        wi0[j] = (v2f){ wih0[r0 * 6 + j] * sxw, wih0[r1 * 6 + j] * syw };
        wh0[j] = (v2f){ whh0[r0 * 6 + j] * sxw, whh0[r1 * 6 + j] * syw };
        wi1[j] = (v2f){ wih1[r0 * 6 + j] * sxw, wih1[r1 * 6 + j] * syw };
        wh1[j] = (v2f){ whh1[r0 * 6 + j] * sxw, whh1[r1 * 6 + j] * syw };
    }
    const v2f bb0 = (v2f){ (bih0[r0] + bhh0[r0]) * sxw, (bih0[r1] + bhh0[r1]) * syw };
    const v2f bb1 = (v2f){ (bih1[r0] + bhh1[r0]) * sxw, (bih1[r1] + bhh1[r1]) * syw };

    // ---- FC head: rows 2*sub, 2*sub+1 (all 32 rows covered by 16 lanes)
    v2f f1w[6];
    const int fr0 = 2 * sub, fr1 = 2 * sub + 1;
#pragma unroll
    for (int j = 0; j < 6; ++j)
        f1w[j] = (v2f){ fc1w_g[fr0 * 6 + j], fc1w_g[fr1 * 6 + j] };
    const v2f  f1b = (v2f){ fc1b_g[fr0], fc1b_g[fr1] };
    const v2f  f2w = (v2f){ fc2w_g[fr0], fc2w_g[fr1] };
    const float f2b = fc2b_g[0];

    // ---- recurrent state
    float h0b[6], h1b[6];
#pragma unroll
    for (int j = 0; j < 6; ++j) { h0b[j] = 0.0f; h1b[j] = 0.0f; }
    float c0 = 0.0f, c1 = 0.0f;

    const float* xp = x + (size_t)seq * (512 * 6);
    float*       op = out + (size_t)seq * 512;

    // xc double-buffer: xcA holds x[t] for even t, xcB for odd t.
    float xcA[6], xcB[6];
    {
        float2 a = *(const float2*)(xp + 0);
        float2 b = *(const float2*)(xp + 2);
        float2 c = *(const float2*)(xp + 4);
        xcA[0] = a.x; xcA[1] = a.y; xcA[2] = b.x; xcA[3] = b.y; xcA[4] = c.x; xcA[5] = c.y;
    }

#define LSTM_STEP(T_, XC_, XN_, LAST_)                                          \
    {                                                                           \
        /* prefetch x[T_+1] into XN_ */                                         \
        if (!(LAST_)) {                                                         \
            const float* xnp = xp + ((T_) + 1) * 6;                             \
            float2 na = *(const float2*)(xnp + 0);                              \
            float2 nb = *(const float2*)(xnp + 2);                              \
            float2 nc = *(const float2*)(xnp + 4);                              \
            XN_[0] = na.x; XN_[1] = na.y; XN_[2] = nb.x;                        \
            XN_[3] = nb.y; XN_[4] = nc.x; XN_[5] = nc.y;                        \
        }                                                                       \
        /* deferred FC head on h1(t-1) */                                       \
        {                                                                       \
            v2f ra = f1b, rb = (v2f){0.0f, 0.0f};                               \
            ra += f1w[0] * h1b[0];  rb += f1w[1] * h1b[1];                      \
            ra += f1w[2] * h1b[2];  rb += f1w[3] * h1b[3];                      \
            ra += f1w[4] * h1b[4];  rb += f1w[5] * h1b[5];                      \
            v2f r = ra + rb;                                                    \
            float acc = f2w.x * fmaxf(r.x, 0.0f) + f2w.y * fmaxf(r.y, 0.0f);    \
            acc += swzf<0x041F>(acc);                                           \
            acc += swzf<0x081F>(acc);                                           \
            acc += swzf<0x101F>(acc);                                           \
            acc += swzf<0x201F>(acc);                                           \
            if ((T_) > 0 && sub == 0) op[(T_) - 1] = fmaxf(acc + f2b, 0.0f);    \
        }                                                                       \
        /* cell1 recurrent partial (h1(t-1) only): hoisted */                   \
        v2f a1a = bb1, a1b = (v2f){0.0f, 0.0f};                                 \
        a1a += wh1[0] * h1b[0];  a1b += wh1[1] * h1b[1];                        \
        a1a += wh1[2] * h1b[2];  a1b += wh1[3] * h1b[3];                        \
        a1a += wh1[4] * h1b[4];  a1b += wh1[5] * h1b[5];                        \
        /* cell 0 gates */                                                      \
        v2f ga = bb0, gb = (v2f){0.0f, 0.0f};                                   \
        ga += wi0[0] * XC_[0];   gb += wi0[1] * XC_[1];                         \
        ga += wi0[2] * XC_[2];   gb += wi0[3] * XC_[3];                         \
        ga += wi0[4] * XC_[4];   gb += wi0[5] * XC_[5];                         \
        ga += wh0[0] * h0b[0];   gb += wh0[1] * h0b[1];                         \
        ga += wh0[2] * h0b[2];   gb += wh0[3] * h0b[3];                         \
        ga += wh0[4] * h0b[4];   gb += wh0[5] * h0b[5];                         \
        v2f gv = ga + gb;                                                       \
        float ax = 1.0f - Bx * __builtin_amdgcn_rcpf(1.0f + __builtin_amdgcn_exp2f(gv.x)); \
        float ay = 1.0f -      __builtin_amdgcn_rcpf(1.0f + __builtin_amdgcn_exp2f(gv.y)); \
        float sx = swzf<0x201F>(ax);                                            \
        float sy = swzf<0x201F>(ay);                                            \
        float fg = half ? sy : ay;                                              \
        float og = half ? ay : sy;                                              \
        c0 = fg * c0 + ax * sx;                                                 \
        float h0 = og * tanh_fast(c0);                                          \
        h0b[0] = bcast16<0>(h0);                                                \
        h0b[1] = bcast16<1>(h0);                                                \
        h0b[2] = bcast16<2>(h0);                                                \
        h0b[3] = bcast16<3>(h0);                                                \
        h0b[4] = bcast16<4>(h0);                                                \
        h0b[5] = bcast16<5>(h0);                                                \
        /* cell 1 gates */                                                      \
        a1a += wi1[0] * h0b[0];  a1b += wi1[1] * h0b[1];                        \
        a1a += wi1[2] * h0b[2];  a1b += wi1[3] * h0b[3];                        \
        a1a += wi1[4] * h0b[4];  a1b += wi1[5] * h0b[5];                        \
        v2f g1 = a1a + a1b;                                                     \
        float ax1 = 1.0f - Bx * __builtin_amdgcn_rcpf(1.0f + __builtin_amdgcn_exp2f(g1.x)); \
        float ay1 = 1.0f -      __builtin_amdgcn_rcpf(1.0f + __builtin_amdgcn_exp2f(g1.y)); \
        float sx1 = swzf<0x201F>(ax1);                                          \
        float sy1 = swzf<0x201F>(ay1);                                          \
        float fg1 = half ? sy1 : ay1;                                           \
        float og1 = half ? ay1 : sy1;                                           \
        c1 = fg1 * c1 + ax1 * sx1;                                              \
        float h1 = og1 * tanh_fast(c1);                                         \
        h1b[0] = bcast16<0>(h1);                                                \
        h1b[1] = bcast16<1>(h1);                                                \
        h1b[2] = bcast16<2>(h1);                                                \
        h1b[3] = bcast16<3>(h1);                                                \
        h1b[4] = bcast16<4>(h1);                                                \
        h1b[5] = bcast16<5>(h1);                                                \
    }

    for (int t = 0; t < 512; t += 2) {
        LSTM_STEP(t,     xcA, xcB, false);
        LSTM_STEP(t + 1, xcB, xcA, (t + 1 == 511));
    }
#undef LSTM_STEP

    // ---- final FC head for t = 511
    {
        v2f ra = f1b, rb = (v2f){0.0f, 0.0f};
        ra += f1w[0] * h1b[0];  rb += f1w[1] * h1b[1];
        ra += f1w[2] * h1b[2];  rb += f1w[3] * h1b[3];
        ra += f1w[4] * h1b[4];  rb += f1w[5] * h1b[5];
        v2f r = ra + rb;
        float acc = f2w.x * fmaxf(r.x, 0.0f) + f2w.y * fmaxf(r.y, 0.0f);
        acc += swzf<0x041F>(acc);
        acc += swzf<0x081F>(acc);
        acc += swzf<0x101F>(acc);
        acc += swzf<0x201F>(acc);
        if (sub == 0) op[511] = fmaxf(acc + f2b, 0.0f);
    }
}

extern "C" void kernel_launch(void* const* d_in, const int* in_sizes, int n_in,
                              void* d_out, int out_size, void* d_ws, size_t ws_size,
                              hipStream_t stream) {
    const float* x     = (const float*)d_in[0];
    const float* wih0  = (const float*)d_in[1];
    const float* whh0  = (const float*)d_in[2];
    const float* bih0  = (const float*)d_in[3];
    const float* bhh0  = (const float*)d_in[4];
    const float* wih1  = (const float*)d_in[5];
    const float* whh1  = (const float*)d_in[6];
    const float* bih1  = (const float*)d_in[7];
    const float* bhh1  = (const float*)d_in[8];
    const float* fc1w  = (const float*)d_in[9];
    const float* fc1b  = (const float*)d_in[10];
    const float* fc2w  = (const float*)d_in[11];
    const float* fc2b  = (const float*)d_in[12];
    float* out = (float*)d_out;

    const int nbatch  = in_sizes[0] / (512 * 6);   // 8192
    const int threads = nbatch * 16;               // 16 lanes per sequence
    const int block   = 256;
    const int grid    = (threads + block - 1) / block;

    hipLaunchKernelGGL(lstm_fused16, dim3(grid), dim3(block), 0, stream,
                       x, wih0, whh0, bih0, bhh0, wih1, whh1, bih1, bhh1,
                       fc1w, fc1b, fc2w, fc2b, out, nbatch);
}